// Round 2
// baseline (9736.690 us; speedup 1.0000x reference)
//
#include <hip/hip_runtime.h>
#include <math.h>

// inputs [32,64,64,64] f32, embedding [1024,64] f32
#define N_ROWS   131072
#define D        64
#define K_EMB    1024
#define M_TILE   128         // rows per block
#define KC       128         // codes staged per chunk
#define LDSTR    68          // padded LDS stride (floats), keeps rows 16B-aligned
#define MARGIN   4e-5f       // fp32-vs-fp64 ambiguity margin (~15x worst-case error bound)

// Output layout (floats): q_st | q_orig | perplexity | encodings
#define Q_ST_OFF   0
#define Q_OR_OFF   8388608
#define PERP_OFF   16777216
#define ENC_OFF    16777217   // odd -> encodings region only 4B-aligned

// ws: [0,4096) uint counts[1024]; [4096,8192) float enorm32[1024]

__global__ __launch_bounds__(256) void enorm32_kernel(const float* __restrict__ emb,
                                                      float* __restrict__ enorm) {
    int k = blockIdx.x * 256 + threadIdx.x;
    const float4* row = reinterpret_cast<const float4*>(emb + (size_t)k * D);
    float s = 0.f;
#pragma unroll
    for (int i = 0; i < 16; ++i) {
        float4 v = row[i];
        s = fmaf(v.x, v.x, s); s = fmaf(v.y, v.y, s);
        s = fmaf(v.z, v.z, s); s = fmaf(v.w, v.w, s);
    }
    enorm[k] = s;
}

__global__ __launch_bounds__(256) void vq_main(const float* __restrict__ in,
                                               const float* __restrict__ emb,
                                               const float* __restrict__ enorm32,
                                               unsigned int* __restrict__ counts,
                                               float* __restrict__ out) {
    __shared__ __align__(16) float Xs[M_TILE][LDSTR];
    __shared__ __align__(16) float Es[KC][LDSTR];
    __shared__ __align__(16) float enorms[K_EMB];
    __shared__ int bks[M_TILE];
    __shared__ int flags[M_TILE];
    __shared__ int flaglist[M_TILE];
    __shared__ int nflag_s;
    __shared__ double redv[4][4];
    __shared__ int    redk[4][4];

    const int tid  = threadIdx.x;
    const int tc   = tid & 15;     // code lane 0..15
    const int trf  = tid >> 4;     // row group 0..15 (4 consecutive per wave -> conflict-free)
    const int base = blockIdx.x * M_TILE;

    if (tid == 0) nflag_s = 0;

    // stage fp32 e-norms (1024 floats)
    {
        float4 v = *reinterpret_cast<const float4*>(enorm32 + tid * 4);
        *reinterpret_cast<float4*>(&enorms[tid * 4]) = v;
    }
    // stage X tile (128x64 f32)
    {
        const float4* src = reinterpret_cast<const float4*>(in + (size_t)base * D);
#pragma unroll
        for (int i = 0; i < 8; ++i) {
            int lin = i * 256 + tid;               // 0..2047
            float4 v = src[lin];
            *reinterpret_cast<float4*>(&Xs[lin >> 4][(lin & 15) << 2]) = v;
        }
    }

    float b1[8], b2[8]; int k1[8];
#pragma unroll
    for (int j = 0; j < 8; ++j) { b1[j] = 1e30f; b2[j] = 1e30f; k1[j] = 0; }

    for (int ch = 0; ch < K_EMB / KC; ++ch) {
        __syncthreads();
        {   // stage E chunk (128x64 f32)
            const float4* esrc = reinterpret_cast<const float4*>(emb + (size_t)ch * KC * D);
#pragma unroll
            for (int i = 0; i < 8; ++i) {
                int lin = i * 256 + tid;
                float4 v = esrc[lin];
                *reinterpret_cast<float4*>(&Es[lin >> 4][(lin & 15) << 2]) = v;
            }
        }
        __syncthreads();

        float acc[8][8];
#pragma unroll
        for (int j = 0; j < 8; ++j)
#pragma unroll
            for (int c = 0; c < 8; ++c) acc[j][c] = 0.f;

#pragma unroll
        for (int db = 0; db < 16; ++db) {
            float4 e4[8];
#pragma unroll
            for (int c = 0; c < 8; ++c)
                e4[c] = *reinterpret_cast<const float4*>(&Es[tc + 16 * c][db * 4]);
#pragma unroll
            for (int j = 0; j < 8; ++j) {
                float4 x4 = *reinterpret_cast<const float4*>(&Xs[trf + 16 * j][db * 4]);
#pragma unroll
                for (int c = 0; c < 8; ++c) {
                    acc[j][c] = fmaf(x4.x, e4[c].x, acc[j][c]);
                    acc[j][c] = fmaf(x4.y, e4[c].y, acc[j][c]);
                    acc[j][c] = fmaf(x4.z, e4[c].z, acc[j][c]);
                    acc[j][c] = fmaf(x4.w, e4[c].w, acc[j][c]);
                }
            }
        }
        // scores + running best/second-best (k ascending within thread -> strict < = first index)
#pragma unroll
        for (int c = 0; c < 8; ++c) {
            int k = ch * KC + tc + 16 * c;
            float en = enorms[k];
#pragma unroll
            for (int j = 0; j < 8; ++j) {
                float s = fmaf(-2.f, acc[j][c], en);
                if (s < b1[j]) { b2[j] = b1[j]; b1[j] = s; k1[j] = k; }
                else if (s < b2[j]) b2[j] = s;
            }
        }
    }

    // reduce (best1,k,best2) across the 16 tc-lanes of each row
#pragma unroll
    for (int j = 0; j < 8; ++j) {
        float v = b1[j], v2 = b2[j]; int kk = k1[j];
#pragma unroll
        for (int off = 8; off >= 1; off >>= 1) {
            float ov  = __shfl_xor(v,  off, 64);
            int   ok  = __shfl_xor(kk, off, 64);
            float ov2 = __shfl_xor(v2, off, 64);
            bool win = (ov < v) || (ov == v && ok < kk);
            float loser = win ? v : ov;
            v2 = fminf(fminf(v2, ov2), loser);
            if (win) { v = ov; kk = ok; }
        }
        if (tc == 0) {
            int row = trf + 16 * j;
            bks[row]   = kk;
            flags[row] = (v2 - v < MARGIN) ? 1 : 0;
        }
    }
    __syncthreads();
    if (tid < M_TILE && flags[tid]) {
        int pos = atomicAdd(&nflag_s, 1);
        flaglist[pos] = tid;
    }

    // zero-fill this block's encodings rows early (stores drain under rescore)
    {
        float* ep = out + ENC_OFF + (size_t)base * K_EMB;   // float idx ≡ 1 (mod 4) globally
        float4 z = make_float4(0.f, 0.f, 0.f, 0.f);
        float4* ap = reinterpret_cast<float4*>(ep + 3);     // 16B-aligned
        for (int i = tid; i < 32767; i += 256) ap[i] = z;
        if (tid == 0) { ep[0] = 0.f; ep[1] = 0.f; ep[2] = 0.f; ep[131071] = 0.f; }
    }
    __syncthreads();

    // fp64 exact rescore of ambiguous rows (expected ~2%), groups of 4 rows
    int nf = nflag_s;
    for (int g0 = 0; g0 < nf; g0 += 4) {
        int rg[4];
#pragma unroll
        for (int t = 0; t < 4; ++t) rg[t] = flaglist[min(g0 + t, nf - 1)];
        double acc[4][4]; double en[4];
#pragma unroll
        for (int c = 0; c < 4; ++c) { en[c] = 0.0;
#pragma unroll
            for (int r = 0; r < 4; ++r) acc[r][c] = 0.0; }
#pragma unroll 4
        for (int db = 0; db < 16; ++db) {
            float4 x4[4], e4[4];
#pragma unroll
            for (int r = 0; r < 4; ++r)
                x4[r] = *reinterpret_cast<const float4*>(&Xs[rg[r]][db * 4]);
#pragma unroll
            for (int c = 0; c < 4; ++c)
                e4[c] = *reinterpret_cast<const float4*>(&emb[(size_t)(tid * 4 + c) * D + db * 4]);
#pragma unroll
            for (int dd = 0; dd < 4; ++dd) {
                double ed[4], xd[4];
#pragma unroll
                for (int c = 0; c < 4; ++c) {
                    ed[c] = (double)((&e4[c].x)[dd]);
                    en[c] = fma(ed[c], ed[c], en[c]);
                }
#pragma unroll
                for (int r = 0; r < 4; ++r) xd[r] = (double)((&x4[r].x)[dd]);
#pragma unroll
                for (int r = 0; r < 4; ++r)
#pragma unroll
                    for (int c = 0; c < 4; ++c) acc[r][c] = fma(xd[r], ed[c], acc[r][c]);
            }
        }
        double bv[4]; int bk[4];
#pragma unroll
        for (int r = 0; r < 4; ++r) { bv[r] = 1e300; bk[r] = 0; }
#pragma unroll
        for (int c = 0; c < 4; ++c) {
            int k = tid * 4 + c;
#pragma unroll
            for (int r = 0; r < 4; ++r) {
                double s = fma(-2.0, acc[r][c], en[c]);
                if (s < bv[r]) { bv[r] = s; bk[r] = k; }
            }
        }
        const int lane = tid & 63, wv = tid >> 6;
#pragma unroll
        for (int r = 0; r < 4; ++r) {
            double v = bv[r]; int kk = bk[r];
#pragma unroll
            for (int off = 32; off >= 1; off >>= 1) {
                double ov = __shfl_xor(v, off, 64);
                int    ok = __shfl_xor(kk, off, 64);
                if (ov < v || (ov == v && ok < kk)) { v = ov; kk = ok; }
            }
            if (lane == 0) { redv[wv][r] = v; redk[wv][r] = kk; }
        }
        __syncthreads();
        if (tid < 4) {
            double v = redv[0][tid]; int kk = redk[0][tid];
#pragma unroll
            for (int w = 1; w < 4; ++w) {
                double ov = redv[w][tid]; int ok = redk[w][tid];
                if (ov < v || (ov == v && ok < kk)) { v = ov; kk = ok; }
            }
            int row = flaglist[min(g0 + tid, nf - 1)];
            bks[row] = kk;      // duplicate-tail writes store identical values
        }
        __syncthreads();
    }
    __syncthreads();

    // one-hot + counts
    if (tid < M_TILE) {
        int kk = bks[tid];
        atomicAdd(&counts[kk], 1u);
        out[ENC_OFF + (size_t)(base + tid) * K_EMB + kk] = 1.0f;
    }
    // quantized copy (both outputs identical): 2 threads per row
    {
        int row = tid >> 1;
        int p   = tid & 1;
        int kk  = bks[row];
        const float4* er = reinterpret_cast<const float4*>(emb + (size_t)kk * D);
        float4* o1 = reinterpret_cast<float4*>(out + Q_ST_OFF + (size_t)(base + row) * D);
        float4* o2 = reinterpret_cast<float4*>(out + Q_OR_OFF + (size_t)(base + row) * D);
#pragma unroll
        for (int i = 0; i < 8; ++i) {
            float4 v = er[p * 8 + i];
            o1[p * 8 + i] = v;
            o2[p * 8 + i] = v;
        }
    }
}

__global__ __launch_bounds__(1024) void perp_kernel(const unsigned int* __restrict__ counts,
                                                    float* __restrict__ out_perp) {
    const int k = threadIdx.x;
    double p = (double)counts[k] * (1.0 / (double)N_ROWS);
    double t = p * log(p + 1e-10);
#pragma unroll
    for (int off = 32; off >= 1; off >>= 1) t += __shfl_down(t, off, 64);
    __shared__ double red[16];
    if ((k & 63) == 0) red[k >> 6] = t;
    __syncthreads();
    if (k < 16) {
        double s = red[k];
#pragma unroll
        for (int off = 8; off >= 1; off >>= 1) s += __shfl_down(s, off, 16);
        if (k == 0) out_perp[0] = (float)exp(-s);
    }
}

extern "C" void kernel_launch(void* const* d_in, const int* in_sizes, int n_in,
                              void* d_out, int out_size, void* d_ws, size_t ws_size,
                              hipStream_t stream) {
    const float* in  = (const float*)d_in[0];
    const float* emb = (const float*)d_in[1];
    float* out = (float*)d_out;
    unsigned int* counts = (unsigned int*)d_ws;
    float* enorm32 = (float*)((char*)d_ws + 4096);

    hipMemsetAsync(d_ws, 0, 4096, stream);
    enorm32_kernel<<<K_EMB / 256, 256, 0, stream>>>(emb, enorm32);
    vq_main<<<N_ROWS / M_TILE, 256, 0, stream>>>(in, emb, enorm32, counts, out);
    perp_kernel<<<1, 1024, 0, stream>>>(counts, out + PERP_OFF);
}

// Round 3
// 9138.909 us; speedup vs baseline: 1.0654x; 1.0654x over previous
//
#include <hip/hip_runtime.h>
#include <math.h>

// inputs [32,64,64,64] f32, embedding [1024,64] f32
#define N_ROWS   131072
#define D        64
#define K_EMB    1024
#define M_TILE   128         // rows per block
#define KC       128         // codes staged per chunk
#define LDSTR    68          // padded LDS stride (floats)
#define MARGIN_ACC 1e-5f     // acc units; = 2e-5 distance units, ~4x worst-case fp32 error

// Output layout (floats): q_st | q_orig | perplexity | encodings
#define Q_ST_OFF   0
#define Q_OR_OFF   8388608
#define PERP_OFF   16777216
#define ENC_OFF    16777217   // odd -> encodings region only 4B-aligned

// ws layout: [0,4096) uint counts[1024]; [4096,4100) uint flagcount;
//            [8192,12288) float enorm32[1024]; [16384, ...) int flaglist[]

__global__ __launch_bounds__(256) void enorm32_kernel(const float* __restrict__ emb,
                                                      float* __restrict__ enorm) {
    int k = blockIdx.x * 256 + threadIdx.x;
    const float4* row = reinterpret_cast<const float4*>(emb + (size_t)k * D);
    float s = 0.f;
#pragma unroll
    for (int i = 0; i < 16; ++i) {
        float4 v = row[i];
        s = fmaf(v.x, v.x, s); s = fmaf(v.y, v.y, s);
        s = fmaf(v.z, v.z, s); s = fmaf(v.w, v.w, s);
    }
    enorm[k] = s;
}

__global__ __launch_bounds__(256) void vq_main(const float* __restrict__ in,
                                               const float* __restrict__ emb,
                                               const float* __restrict__ enorm32,
                                               unsigned int* __restrict__ counts,
                                               unsigned int* __restrict__ flagcount,
                                               int* __restrict__ flaglist,
                                               int flagcap,
                                               float* __restrict__ out) {
    __shared__ __align__(16) float Xs[M_TILE][LDSTR];
    __shared__ __align__(16) float Es[KC][LDSTR];
    __shared__ __align__(16) float enorms[K_EMB];
    __shared__ int bks[M_TILE];

    const int tid  = threadIdx.x;
    const int tc   = tid & 15;     // code lane 0..15
    const int trf  = tid >> 4;     // row group 0..15
    const int base = blockIdx.x * M_TILE;

    // stage fp32 e-norms (1024 floats)
    {
        float4 v = *reinterpret_cast<const float4*>(enorm32 + tid * 4);
        *reinterpret_cast<float4*>(&enorms[tid * 4]) = v;
    }
    // stage X tile (128x64 f32)
    {
        const float4* src = reinterpret_cast<const float4*>(in + (size_t)base * D);
#pragma unroll
        for (int i = 0; i < 8; ++i) {
            int lin = i * 256 + tid;
            float4 v = src[lin];
            *reinterpret_cast<float4*>(&Xs[lin >> 4][(lin & 15) << 2]) = v;
        }
    }

    // maximize acc = x.e - ||e||^2/2  (argmax acc == argmin distance)
    float b1[8], b2[8]; int k1[8];
#pragma unroll
    for (int j = 0; j < 8; ++j) { b1[j] = -1e30f; b2[j] = -1e30f; k1[j] = 0; }

    for (int ch = 0; ch < K_EMB / KC; ++ch) {
        __syncthreads();
        {   // stage E chunk (128x64 f32)
            const float4* esrc = reinterpret_cast<const float4*>(emb + (size_t)ch * KC * D);
#pragma unroll
            for (int i = 0; i < 8; ++i) {
                int lin = i * 256 + tid;
                float4 v = esrc[lin];
                *reinterpret_cast<float4*>(&Es[lin >> 4][(lin & 15) << 2]) = v;
            }
        }
        __syncthreads();

        float acc[8][8];
#pragma unroll
        for (int c = 0; c < 8; ++c) {
            float nh = -0.5f * enorms[ch * KC + tc + 16 * c];
#pragma unroll
            for (int j = 0; j < 8; ++j) acc[j][c] = nh;
        }

#pragma unroll
        for (int db = 0; db < 16; ++db) {
            float4 e4[8];
#pragma unroll
            for (int c = 0; c < 8; ++c)
                e4[c] = *reinterpret_cast<const float4*>(&Es[tc + 16 * c][db * 4]);
#pragma unroll
            for (int j = 0; j < 8; ++j) {
                float4 x4 = *reinterpret_cast<const float4*>(&Xs[trf + 16 * j][db * 4]);
#pragma unroll
                for (int c = 0; c < 8; ++c) {
                    acc[j][c] = fmaf(x4.x, e4[c].x, acc[j][c]);
                    acc[j][c] = fmaf(x4.y, e4[c].y, acc[j][c]);
                    acc[j][c] = fmaf(x4.z, e4[c].z, acc[j][c]);
                    acc[j][c] = fmaf(x4.w, e4[c].w, acc[j][c]);
                }
            }
        }
        // running best / second-best (k ascending in thread -> strict > keeps first index)
#pragma unroll
        for (int c = 0; c < 8; ++c) {
            int k = ch * KC + tc + 16 * c;
#pragma unroll
            for (int j = 0; j < 8; ++j) {
                float s = acc[j][c];
                if (s > b1[j]) { b2[j] = b1[j]; b1[j] = s; k1[j] = k; }
                else if (s > b2[j]) b2[j] = s;
            }
        }
    }

    // reduce (best1,k,best2) across the 16 tc-lanes of each row
#pragma unroll
    for (int j = 0; j < 8; ++j) {
        float v = b1[j], v2 = b2[j]; int kk = k1[j];
#pragma unroll
        for (int off = 8; off >= 1; off >>= 1) {
            float ov  = __shfl_xor(v,  off, 64);
            int   ok  = __shfl_xor(kk, off, 64);
            float ov2 = __shfl_xor(v2, off, 64);
            bool win = (ov > v) || (ov == v && ok < kk);
            float loser = win ? v : ov;
            v2 = fmaxf(fmaxf(v2, ov2), loser);
            if (win) { v = ov; kk = ok; }
        }
        if (tc == 0) {
            int row = trf + 16 * j;
            bks[row] = kk;
            if (v - v2 < MARGIN_ACC) {           // ambiguous -> exact fp64 rescore later
                int pos = (int)atomicAdd(flagcount, 1u);
                if (pos < flagcap) flaglist[pos] = ((base + row) << 10) | kk;
            }
        }
    }

    // zero-fill this block's encodings rows (128*1024 f32; region 4B-aligned only)
    {
        float* ep = out + ENC_OFF + (size_t)base * K_EMB;   // float idx ≡ 1 (mod 4)
        float4 z = make_float4(0.f, 0.f, 0.f, 0.f);
        float4* ap = reinterpret_cast<float4*>(ep + 3);
        for (int i = tid; i < 32767; i += 256) ap[i] = z;
        if (tid == 0) { ep[0] = 0.f; ep[1] = 0.f; ep[2] = 0.f; ep[131071] = 0.f; }
    }
    __syncthreads();   // bks visible + zeros ordered before one-hot

    // one-hot + counts
    if (tid < M_TILE) {
        int kk = bks[tid];
        atomicAdd(&counts[kk], 1u);
        out[ENC_OFF + (size_t)(base + tid) * K_EMB + kk] = 1.0f;
    }
    // quantized copy (both outputs identical): 2 threads per row
    {
        int row = tid >> 1;
        int p   = tid & 1;
        int kk  = bks[row];
        const float4* er = reinterpret_cast<const float4*>(emb + (size_t)kk * D);
        float4* o1 = reinterpret_cast<float4*>(out + Q_ST_OFF + (size_t)(base + row) * D);
        float4* o2 = reinterpret_cast<float4*>(out + Q_OR_OFF + (size_t)(base + row) * D);
#pragma unroll
        for (int i = 0; i < 8; ++i) {
            float4 v = er[p * 8 + i];
            o1[p * 8 + i] = v;
            o2[p * 8 + i] = v;
        }
    }
}

// Exact fp64 rescore of flagged rows; patches encodings/quantized/counts in place.
__global__ __launch_bounds__(256) void rescore_kernel(const float* __restrict__ in,
                                                      const float* __restrict__ emb,
                                                      const unsigned int* __restrict__ flagcount,
                                                      const int* __restrict__ flaglist,
                                                      int flagcap,
                                                      unsigned int* __restrict__ counts,
                                                      float* __restrict__ out) {
    __shared__ __align__(16) float xs[64];
    __shared__ double rv[4];
    __shared__ int    rk[4];
    __shared__ int    oldk_s;

    const int tid = threadIdx.x;
    int nf = (int)*flagcount;
    bool overflow = nf > flagcap;              // pathological ws_size fallback
    int total = overflow ? N_ROWS : nf;

    for (int idx = blockIdx.x; idx < total; idx += gridDim.x) {
        int row, oldk;
        if (!overflow) {
            int e = flaglist[idx];
            row = e >> 10; oldk = e & 1023;
        } else {
            row = idx; oldk = -1;
        }
        if (tid < 16)
            *reinterpret_cast<float4*>(&xs[tid * 4]) =
                reinterpret_cast<const float4*>(in + (size_t)row * D)[tid];
        __syncthreads();
        if (overflow) {                        // recover oldk from the one-hot row
            const float* er = out + ENC_OFF + (size_t)row * K_EMB;
#pragma unroll
            for (int c = 0; c < 4; ++c)
                if (er[tid * 4 + c] == 1.0f) oldk_s = tid * 4 + c;
            __syncthreads();
            oldk = oldk_s;
        }

        double bv = 1e300; int bk = 0;
#pragma unroll
        for (int c = 0; c < 4; ++c) {
            int k = tid * 4 + c;
            const float4* er = reinterpret_cast<const float4*>(emb + (size_t)k * D);
            double dot = 0.0, en = 0.0;
#pragma unroll 4
            for (int i = 0; i < 16; ++i) {
                float4 ev = er[i];
                float4 xv = *reinterpret_cast<const float4*>(&xs[i * 4]);
                double e0 = ev.x, e1 = ev.y, e2 = ev.z, e3 = ev.w;
                en  = fma(e0, e0, en);  en  = fma(e1, e1, en);
                en  = fma(e2, e2, en);  en  = fma(e3, e3, en);
                dot = fma((double)xv.x, e0, dot); dot = fma((double)xv.y, e1, dot);
                dot = fma((double)xv.z, e2, dot); dot = fma((double)xv.w, e3, dot);
            }
            double s = fma(-2.0, dot, en);
            if (s < bv) { bv = s; bk = k; }    // k ascending -> first index
        }
        const int lane = tid & 63, wv = tid >> 6;
        {
            double v = bv; int kk = bk;
#pragma unroll
            for (int off = 32; off >= 1; off >>= 1) {
                double ov = __shfl_xor(v, off, 64);
                int    ok = __shfl_xor(kk, off, 64);
                if (ov < v || (ov == v && ok < kk)) { v = ov; kk = ok; }
            }
            if (lane == 0) { rv[wv] = v; rk[wv] = kk; }
        }
        __syncthreads();
        if (tid == 0) {
            double v = rv[0]; int kk = rk[0];
#pragma unroll
            for (int w = 1; w < 4; ++w) {
                double ov = rv[w]; int ok = rk[w];
                if (ov < v || (ov == v && ok < kk)) { v = ov; kk = ok; }
            }
            if (kk != oldk) {
                out[ENC_OFF + (size_t)row * K_EMB + oldk] = 0.0f;
                out[ENC_OFF + (size_t)row * K_EMB + kk]   = 1.0f;
                atomicAdd(&counts[oldk], (unsigned int)-1);
                atomicAdd(&counts[kk], 1u);
                const float4* er = reinterpret_cast<const float4*>(emb + (size_t)kk * D);
                float4* o1 = reinterpret_cast<float4*>(out + Q_ST_OFF + (size_t)row * D);
                float4* o2 = reinterpret_cast<float4*>(out + Q_OR_OFF + (size_t)row * D);
#pragma unroll
                for (int i = 0; i < 16; ++i) { float4 vv = er[i]; o1[i] = vv; o2[i] = vv; }
            }
        }
        __syncthreads();
    }
}

__global__ __launch_bounds__(1024) void perp_kernel(const unsigned int* __restrict__ counts,
                                                    float* __restrict__ out_perp) {
    const int k = threadIdx.x;
    double p = (double)counts[k] * (1.0 / (double)N_ROWS);
    double t = p * log(p + 1e-10);
#pragma unroll
    for (int off = 32; off >= 1; off >>= 1) t += __shfl_down(t, off, 64);
    __shared__ double red[16];
    if ((k & 63) == 0) red[k >> 6] = t;
    __syncthreads();
    if (k < 16) {
        double s = red[k];
#pragma unroll
        for (int off = 8; off >= 1; off >>= 1) s += __shfl_down(s, off, 16);
        if (k == 0) out_perp[0] = (float)exp(-s);
    }
}

extern "C" void kernel_launch(void* const* d_in, const int* in_sizes, int n_in,
                              void* d_out, int out_size, void* d_ws, size_t ws_size,
                              hipStream_t stream) {
    const float* in  = (const float*)d_in[0];
    const float* emb = (const float*)d_in[1];
    float* out = (float*)d_out;
    unsigned int* counts    = (unsigned int*)d_ws;
    unsigned int* flagcount = (unsigned int*)((char*)d_ws + 4096);
    float* enorm32          = (float*)((char*)d_ws + 8192);
    int*   flaglist         = (int*)((char*)d_ws + 16384);
    int flagcap = (ws_size > 16384) ? (int)((ws_size - 16384) / 4) : 0;
    if (flagcap > N_ROWS) flagcap = N_ROWS;

    hipMemsetAsync(d_ws, 0, 8192, stream);   // counts + flagcount
    enorm32_kernel<<<K_EMB / 256, 256, 0, stream>>>(emb, enorm32);
    vq_main<<<N_ROWS / M_TILE, 256, 0, stream>>>(in, emb, enorm32, counts,
                                                 flagcount, flaglist, flagcap, out);
    rescore_kernel<<<1024, 256, 0, stream>>>(in, emb, flagcount, flaglist, flagcap,
                                             counts, out);
    perp_kernel<<<1, 1024, 0, stream>>>(counts, out + PERP_OFF);
}

// Round 4
// 902.331 us; speedup vs baseline: 10.7906x; 10.1281x over previous
//
#include <hip/hip_runtime.h>
#include <math.h>

// inputs [32,64,64,64] f32, embedding [1024,64] f32
#define N_ROWS   131072
#define D        64
#define K_EMB    1024
#define M_TILE   128         // rows per block
#define KC       128         // codes staged per chunk
#define LDSTR    68          // padded LDS stride (floats)
#define MARGIN_ACC 1e-6f     // acc units (= 2e-6 distance); fp32 worst-case err ~2.4e-7

// Output layout (floats): q_st | q_orig | perplexity | encodings
#define Q_ST_OFF   0
#define Q_OR_OFF   8388608
#define PERP_OFF   16777216
#define ENC_OFF    16777217   // odd -> encodings region only 4B-aligned

// ws layout: [0,4096) uint counts[1024]; [4096,4100) uint flagcount;
//            [8192,12288) float enorm32[1024]; [16384, ...) int flaglist[]

__global__ __launch_bounds__(256) void enorm32_kernel(const float* __restrict__ emb,
                                                      float* __restrict__ enorm) {
    int k = blockIdx.x * 256 + threadIdx.x;
    const float4* row = reinterpret_cast<const float4*>(emb + (size_t)k * D);
    float s = 0.f;
#pragma unroll
    for (int i = 0; i < 16; ++i) {
        float4 v = row[i];
        s = fmaf(v.x, v.x, s); s = fmaf(v.y, v.y, s);
        s = fmaf(v.z, v.z, s); s = fmaf(v.w, v.w, s);
    }
    enorm[k] = s;
}

__global__ __launch_bounds__(256) void vq_main(const float* __restrict__ in,
                                               const float* __restrict__ emb,
                                               const float* __restrict__ enorm32,
                                               unsigned int* __restrict__ counts,
                                               unsigned int* __restrict__ flagcount,
                                               int* __restrict__ flaglist,
                                               int flagcap,
                                               float* __restrict__ out) {
    __shared__ __align__(16) float Xs[M_TILE][LDSTR];
    __shared__ __align__(16) float Es[KC][LDSTR];
    __shared__ __align__(16) float enorms[K_EMB];
    __shared__ int bks[M_TILE];

    const int tid  = threadIdx.x;
    const int tc   = tid & 15;     // code lane 0..15
    const int trf  = tid >> 4;     // row group 0..15
    const int base = blockIdx.x * M_TILE;

    // stage fp32 e-norms (1024 floats)
    {
        float4 v = *reinterpret_cast<const float4*>(enorm32 + tid * 4);
        *reinterpret_cast<float4*>(&enorms[tid * 4]) = v;
    }
    // stage X tile (128x64 f32)
    {
        const float4* src = reinterpret_cast<const float4*>(in + (size_t)base * D);
#pragma unroll
        for (int i = 0; i < 8; ++i) {
            int lin = i * 256 + tid;
            float4 v = src[lin];
            *reinterpret_cast<float4*>(&Xs[lin >> 4][(lin & 15) << 2]) = v;
        }
    }

    // maximize acc = x.e - ||e||^2/2  (argmax acc == argmin distance)
    float b1[8], b2[8]; int k1[8];
#pragma unroll
    for (int j = 0; j < 8; ++j) { b1[j] = -1e30f; b2[j] = -1e30f; k1[j] = 0; }

    const float* xsb = &Xs[trf][0];   // row stride 16*LDSTR floats per j
    const float* esb = &Es[tc][0];    // row stride 16*LDSTR floats per c

    for (int ch = 0; ch < K_EMB / KC; ++ch) {
        __syncthreads();
        {   // stage E chunk (128x64 f32)
            const float4* esrc = reinterpret_cast<const float4*>(emb + (size_t)ch * KC * D);
#pragma unroll
            for (int i = 0; i < 8; ++i) {
                int lin = i * 256 + tid;
                float4 v = esrc[lin];
                *reinterpret_cast<float4*>(&Es[lin >> 4][(lin & 15) << 2]) = v;
            }
        }
        __syncthreads();

        float acc[8][8];
#pragma unroll
        for (int c = 0; c < 8; ++c) {
            float nh = -0.5f * enorms[ch * KC + tc + 16 * c];
#pragma unroll
            for (int j = 0; j < 8; ++j) acc[j][c] = nh;
        }

        // rolled K-dim loop: 16 ds_read_b128 + 256 FMA per iter; fence stops
        // cross-iteration hoisting (round-2/3 full unroll spilled acc -> 18 GB scratch)
#pragma unroll 1
        for (int db = 0; db < 16; ++db) {
            float4 e4[8];
#pragma unroll
            for (int c = 0; c < 8; ++c)
                e4[c] = *reinterpret_cast<const float4*>(esb + c * (16 * LDSTR) + db * 4);
#pragma unroll
            for (int j = 0; j < 8; ++j) {
                float4 x4 = *reinterpret_cast<const float4*>(xsb + j * (16 * LDSTR) + db * 4);
#pragma unroll
                for (int c = 0; c < 8; ++c) {
                    acc[j][c] = fmaf(x4.x, e4[c].x, acc[j][c]);
                    acc[j][c] = fmaf(x4.y, e4[c].y, acc[j][c]);
                    acc[j][c] = fmaf(x4.z, e4[c].z, acc[j][c]);
                    acc[j][c] = fmaf(x4.w, e4[c].w, acc[j][c]);
                }
            }
            asm volatile("" ::: "memory");
        }

        // running best / second-best (k ascending in thread -> strict > keeps first index)
#pragma unroll
        for (int c = 0; c < 8; ++c) {
            int k = ch * KC + tc + 16 * c;
#pragma unroll
            for (int j = 0; j < 8; ++j) {
                float s = acc[j][c];
                if (s > b1[j]) { b2[j] = b1[j]; b1[j] = s; k1[j] = k; }
                else if (s > b2[j]) b2[j] = s;
            }
        }
    }

    // reduce (best1,k,best2) across the 16 tc-lanes of each row
#pragma unroll
    for (int j = 0; j < 8; ++j) {
        float v = b1[j], v2 = b2[j]; int kk = k1[j];
#pragma unroll
        for (int off = 8; off >= 1; off >>= 1) {
            float ov  = __shfl_xor(v,  off, 64);
            int   ok  = __shfl_xor(kk, off, 64);
            float ov2 = __shfl_xor(v2, off, 64);
            bool win = (ov > v) || (ov == v && ok < kk);
            float loser = win ? v : ov;
            v2 = fmaxf(fmaxf(v2, ov2), loser);
            if (win) { v = ov; kk = ok; }
        }
        if (tc == 0) {
            int row = trf + 16 * j;
            bks[row] = kk;
            if (v - v2 < MARGIN_ACC) {           // ambiguous -> exact fp64 rescore later
                int pos = (int)atomicAdd(flagcount, 1u);
                if (pos < flagcap) flaglist[pos] = ((base + row) << 10) | kk;
            }
        }
    }

    // zero-fill this block's encodings rows (128*1024 f32; region 4B-aligned only)
    {
        float* ep = out + ENC_OFF + (size_t)base * K_EMB;   // float idx ≡ 1 (mod 4)
        float4 z = make_float4(0.f, 0.f, 0.f, 0.f);
        float4* ap = reinterpret_cast<float4*>(ep + 3);
        for (int i = tid; i < 32767; i += 256) ap[i] = z;
        if (tid == 0) { ep[0] = 0.f; ep[1] = 0.f; ep[2] = 0.f; ep[131071] = 0.f; }
    }
    __syncthreads();   // bks visible + zeros ordered before one-hot

    // one-hot + counts
    if (tid < M_TILE) {
        int kk = bks[tid];
        atomicAdd(&counts[kk], 1u);
        out[ENC_OFF + (size_t)(base + tid) * K_EMB + kk] = 1.0f;
    }
    // quantized copy (both outputs identical): 2 threads per row
    {
        int row = tid >> 1;
        int p   = tid & 1;
        int kk  = bks[row];
        const float4* er = reinterpret_cast<const float4*>(emb + (size_t)kk * D);
        float4* o1 = reinterpret_cast<float4*>(out + Q_ST_OFF + (size_t)(base + row) * D);
        float4* o2 = reinterpret_cast<float4*>(out + Q_OR_OFF + (size_t)(base + row) * D);
#pragma unroll
        for (int i = 0; i < 8; ++i) {
            float4 v = er[p * 8 + i];
            o1[p * 8 + i] = v;
            o2[p * 8 + i] = v;
        }
    }
}

// Exact fp64 rescore of flagged rows; patches encodings/quantized/counts in place.
__global__ __launch_bounds__(256) void rescore_kernel(const float* __restrict__ in,
                                                      const float* __restrict__ emb,
                                                      const unsigned int* __restrict__ flagcount,
                                                      const int* __restrict__ flaglist,
                                                      int flagcap,
                                                      unsigned int* __restrict__ counts,
                                                      float* __restrict__ out) {
    __shared__ __align__(16) float xs[64];
    __shared__ double rv[4];
    __shared__ int    rk[4];
    __shared__ int    oldk_s;

    const int tid = threadIdx.x;
    int nf = (int)*flagcount;
    bool overflow = nf > flagcap;              // pathological ws_size fallback
    int total = overflow ? N_ROWS : nf;

    for (int idx = blockIdx.x; idx < total; idx += gridDim.x) {
        int row, oldk;
        if (!overflow) {
            int e = flaglist[idx];
            row = e >> 10; oldk = e & 1023;
        } else {
            row = idx; oldk = -1;
        }
        if (tid < 16)
            *reinterpret_cast<float4*>(&xs[tid * 4]) =
                reinterpret_cast<const float4*>(in + (size_t)row * D)[tid];
        __syncthreads();
        if (overflow) {                        // recover oldk from the one-hot row
            const float* er = out + ENC_OFF + (size_t)row * K_EMB;
#pragma unroll
            for (int c = 0; c < 4; ++c)
                if (er[tid * 4 + c] == 1.0f) oldk_s = tid * 4 + c;
            __syncthreads();
            oldk = oldk_s;
        }

        double bv = 1e300; int bk = 0;
#pragma unroll
        for (int c = 0; c < 4; ++c) {
            int k = tid * 4 + c;
            const float4* er = reinterpret_cast<const float4*>(emb + (size_t)k * D);
            double dot = 0.0, en = 0.0;
#pragma unroll 4
            for (int i = 0; i < 16; ++i) {
                float4 ev = er[i];
                float4 xv = *reinterpret_cast<const float4*>(&xs[i * 4]);
                double e0 = ev.x, e1 = ev.y, e2 = ev.z, e3 = ev.w;
                en  = fma(e0, e0, en);  en  = fma(e1, e1, en);
                en  = fma(e2, e2, en);  en  = fma(e3, e3, en);
                dot = fma((double)xv.x, e0, dot); dot = fma((double)xv.y, e1, dot);
                dot = fma((double)xv.z, e2, dot); dot = fma((double)xv.w, e3, dot);
            }
            double s = fma(-2.0, dot, en);
            if (s < bv) { bv = s; bk = k; }    // k ascending -> first index
        }
        const int lane = tid & 63, wv = tid >> 6;
        {
            double v = bv; int kk = bk;
#pragma unroll
            for (int off = 32; off >= 1; off >>= 1) {
                double ov = __shfl_xor(v, off, 64);
                int    ok = __shfl_xor(kk, off, 64);
                if (ov < v || (ov == v && ok < kk)) { v = ov; kk = ok; }
            }
            if (lane == 0) { rv[wv] = v; rk[wv] = kk; }
        }
        __syncthreads();
        if (tid == 0) {
            double v = rv[0]; int kk = rk[0];
#pragma unroll
            for (int w = 1; w < 4; ++w) {
                double ov = rv[w]; int ok = rk[w];
                if (ov < v || (ov == v && ok < kk)) { v = ov; kk = ok; }
            }
            if (kk != oldk) {
                out[ENC_OFF + (size_t)row * K_EMB + oldk] = 0.0f;
                out[ENC_OFF + (size_t)row * K_EMB + kk]   = 1.0f;
                atomicAdd(&counts[oldk], (unsigned int)-1);
                atomicAdd(&counts[kk], 1u);
                const float4* er = reinterpret_cast<const float4*>(emb + (size_t)kk * D);
                float4* o1 = reinterpret_cast<float4*>(out + Q_ST_OFF + (size_t)row * D);
                float4* o2 = reinterpret_cast<float4*>(out + Q_OR_OFF + (size_t)row * D);
#pragma unroll
                for (int i = 0; i < 16; ++i) { float4 vv = er[i]; o1[i] = vv; o2[i] = vv; }
            }
        }
        __syncthreads();
    }
}

__global__ __launch_bounds__(1024) void perp_kernel(const unsigned int* __restrict__ counts,
                                                    float* __restrict__ out_perp) {
    const int k = threadIdx.x;
    double p = (double)counts[k] * (1.0 / (double)N_ROWS);
    double t = p * log(p + 1e-10);
#pragma unroll
    for (int off = 32; off >= 1; off >>= 1) t += __shfl_down(t, off, 64);
    __shared__ double red[16];
    if ((k & 63) == 0) red[k >> 6] = t;
    __syncthreads();
    if (k < 16) {
        double s = red[k];
#pragma unroll
        for (int off = 8; off >= 1; off >>= 1) s += __shfl_down(s, off, 16);
        if (k == 0) out_perp[0] = (float)exp(-s);
    }
}

extern "C" void kernel_launch(void* const* d_in, const int* in_sizes, int n_in,
                              void* d_out, int out_size, void* d_ws, size_t ws_size,
                              hipStream_t stream) {
    const float* in  = (const float*)d_in[0];
    const float* emb = (const float*)d_in[1];
    float* out = (float*)d_out;
    unsigned int* counts    = (unsigned int*)d_ws;
    unsigned int* flagcount = (unsigned int*)((char*)d_ws + 4096);
    float* enorm32          = (float*)((char*)d_ws + 8192);
    int*   flaglist         = (int*)((char*)d_ws + 16384);
    int flagcap = (ws_size > 16384) ? (int)((ws_size - 16384) / 4) : 0;
    if (flagcap > N_ROWS) flagcap = N_ROWS;

    hipMemsetAsync(d_ws, 0, 8192, stream);   // counts + flagcount
    enorm32_kernel<<<K_EMB / 256, 256, 0, stream>>>(emb, enorm32);
    vq_main<<<N_ROWS / M_TILE, 256, 0, stream>>>(in, emb, enorm32, counts,
                                                 flagcount, flaglist, flagcap, out);
    rescore_kernel<<<1024, 256, 0, stream>>>(in, emb, flagcount, flaglist, flagcap,
                                             counts, out);
    perp_kernel<<<1, 1024, 0, stream>>>(counts, out + PERP_OFF);
}

// Round 5
// 840.135 us; speedup vs baseline: 11.5894x; 1.0740x over previous
//
#include <hip/hip_runtime.h>
#include <math.h>

// inputs [32,64,64,64] f32, embedding [1024,64] f32
#define N_ROWS 131072
#define D      64
#define K_EMB  1024
#define M_TILE 128         // rows per block (4 waves x 32)
#define KC     128         // codes staged per chunk
#define XSTR   72          // bf16 row stride: 144B = 16B-aligned, odd-16 -> low bank alias
#define MARGIN_D 1e-5f     // distance-units margin; split-bf16 worst-case err ~3e-6

// Output layout (floats): q_st | q_orig | perplexity | encodings
#define Q_ST_OFF 0
#define Q_OR_OFF 8388608
#define PERP_OFF 16777216
#define ENC_OFF  16777217  // odd -> encodings region only 4B-aligned

// ws: [0,4096) uint counts[1024]; [8192,12288) float enorm32[1024]

typedef __attribute__((ext_vector_type(8)))  short bf16x8;
typedef __attribute__((ext_vector_type(16))) float f32x16;

__device__ __forceinline__ unsigned short f2bf_rne(float f) {
    unsigned int u = __float_as_uint(f);
    unsigned int r = u + 0x7fffu + ((u >> 16) & 1u);
    return (unsigned short)(r >> 16);
}
__device__ __forceinline__ float bf2f(unsigned short h) {
    return __uint_as_float(((unsigned int)h) << 16);
}

__global__ __launch_bounds__(256) void enorm32_kernel(const float* __restrict__ emb,
                                                      float* __restrict__ enorm) {
    int k = blockIdx.x * 256 + threadIdx.x;
    const float4* row = reinterpret_cast<const float4*>(emb + (size_t)k * D);
    float s = 0.f;
#pragma unroll
    for (int i = 0; i < 16; ++i) {
        float4 v = row[i];
        s = fmaf(v.x, v.x, s); s = fmaf(v.y, v.y, s);
        s = fmaf(v.z, v.z, s); s = fmaf(v.w, v.w, s);
    }
    enorm[k] = s;
}

__global__ __launch_bounds__(256) void vq_main(const float* __restrict__ in,
                                               const float* __restrict__ emb,
                                               const float* __restrict__ enorm32,
                                               unsigned int* __restrict__ counts,
                                               float* __restrict__ out) {
    __shared__ __align__(16) unsigned short XH[M_TILE * XSTR];
    __shared__ __align__(16) unsigned short XL[M_TILE * XSTR];
    __shared__ __align__(16) unsigned short EH[KC * XSTR];
    __shared__ __align__(16) unsigned short EL[KC * XSTR];
    __shared__ __align__(16) float en_s[K_EMB];
    __shared__ __align__(16) float xs2[D];
    __shared__ int bks[M_TILE];
    __shared__ int flagl[M_TILE];
    __shared__ int nflag;
    __shared__ double rv[4];
    __shared__ int    rk[4];

    const int tid  = threadIdx.x;
    const int lane = tid & 63;
    const int w    = tid >> 6;          // wave 0..3
    const int hl   = lane >> 5;         // k-half select
    const int l31  = lane & 31;
    const int base = blockIdx.x * M_TILE;
    const int wrow = w * 32;

    if (tid == 0) nflag = 0;
    // stage fp32 e-norms
    {
        float4 v = *reinterpret_cast<const float4*>(enorm32 + tid * 4);
        *reinterpret_cast<float4*>(&en_s[tid * 4]) = v;
    }
    // stage X (128x64 f32) -> bf16 hi/lo split
    {
        const float4* src = reinterpret_cast<const float4*>(in + (size_t)base * D);
#pragma unroll
        for (int i = 0; i < 8; ++i) {
            int lin = i * 256 + tid;            // 0..2047
            float4 v = src[lin];
            int row = lin >> 4, c4 = lin & 15;
            ushort4 h, l;
            h.x = f2bf_rne(v.x); l.x = f2bf_rne(v.x - bf2f(h.x));
            h.y = f2bf_rne(v.y); l.y = f2bf_rne(v.y - bf2f(h.y));
            h.z = f2bf_rne(v.z); l.z = f2bf_rne(v.z - bf2f(h.z));
            h.w = f2bf_rne(v.w); l.w = f2bf_rne(v.w - bf2f(h.w));
            *reinterpret_cast<ushort4*>(&XH[row * XSTR + c4 * 4]) = h;
            *reinterpret_cast<ushort4*>(&XL[row * XSTR + c4 * 4]) = l;
        }
    }
    __syncthreads();

    // A fragments (held in regs whole kernel): row = wrow + l31, k-half = hl
    bf16x8 AH[4], AL[4];
    {
        const unsigned short* xh = &XH[(wrow + l31) * XSTR + hl * 8];
        const unsigned short* xl = &XL[(wrow + l31) * XSTR + hl * 8];
#pragma unroll
        for (int kb = 0; kb < 4; ++kb) {
            AH[kb] = *reinterpret_cast<const bf16x8*>(xh + kb * 16);
            AL[kb] = *reinterpret_cast<const bf16x8*>(xl + kb * 16);
        }
    }

    float b1[16], b2[16]; int k1[16];
#pragma unroll
    for (int r = 0; r < 16; ++r) { b1[r] = 1e30f; b2[r] = 1e30f; k1[r] = 0; }

#pragma unroll 1
    for (int ch = 0; ch < K_EMB / KC; ++ch) {
        __syncthreads();
        {   // stage E chunk -> bf16 hi/lo
            const float4* esrc = reinterpret_cast<const float4*>(emb + (size_t)ch * KC * D);
#pragma unroll
            for (int i = 0; i < 8; ++i) {
                int lin = i * 256 + tid;
                float4 v = esrc[lin];
                int row = lin >> 4, c4 = lin & 15;
                ushort4 h, l;
                h.x = f2bf_rne(v.x); l.x = f2bf_rne(v.x - bf2f(h.x));
                h.y = f2bf_rne(v.y); l.y = f2bf_rne(v.y - bf2f(h.y));
                h.z = f2bf_rne(v.z); l.z = f2bf_rne(v.z - bf2f(h.z));
                h.w = f2bf_rne(v.w); l.w = f2bf_rne(v.w - bf2f(h.w));
                *reinterpret_cast<ushort4*>(&EH[row * XSTR + c4 * 4]) = h;
                *reinterpret_cast<ushort4*>(&EL[row * XSTR + c4 * 4]) = l;
            }
        }
        __syncthreads();

#pragma unroll 1
        for (int sub = 0; sub < 4; ++sub) {
            const unsigned short* eh = &EH[(sub * 32 + l31) * XSTR + hl * 8];
            const unsigned short* el = &EL[(sub * 32 + l31) * XSTR + hl * 8];
            bf16x8 BH[4], BL[4];
#pragma unroll
            for (int kb = 0; kb < 4; ++kb) {
                BH[kb] = *reinterpret_cast<const bf16x8*>(eh + kb * 16);
                BL[kb] = *reinterpret_cast<const bf16x8*>(el + kb * 16);
            }
            f32x16 acc = {};
#pragma unroll
            for (int kb = 0; kb < 4; ++kb)
                acc = __builtin_amdgcn_mfma_f32_32x32x16_bf16(AH[kb], BH[kb], acc, 0, 0, 0);
#pragma unroll
            for (int kb = 0; kb < 4; ++kb)
                acc = __builtin_amdgcn_mfma_f32_32x32x16_bf16(AH[kb], BL[kb], acc, 0, 0, 0);
#pragma unroll
            for (int kb = 0; kb < 4; ++kb)
                acc = __builtin_amdgcn_mfma_f32_32x32x16_bf16(AL[kb], BH[kb], acc, 0, 0, 0);

            int kg = ch * KC + sub * 32 + l31;    // this lane's code (column)
            float en = en_s[kg];
#pragma unroll
            for (int r = 0; r < 16; ++r) {
                float s = fmaf(-2.f, acc[r], en);  // distance - ||x||^2
                if (s < b1[r]) { b2[r] = b1[r]; b1[r] = s; k1[r] = kg; }
                else if (s < b2[r]) b2[r] = s;
            }
            asm volatile("" ::: "memory");
        }
    }

    // reduce (b1,k1,b2) across the 32 column-lanes of each half
#pragma unroll
    for (int r = 0; r < 16; ++r) {
        float v = b1[r], v2 = b2[r]; int kk = k1[r];
#pragma unroll
        for (int off = 16; off >= 1; off >>= 1) {
            float ov  = __shfl_xor(v,  off, 64);
            int   ok  = __shfl_xor(kk, off, 64);
            float ov2 = __shfl_xor(v2, off, 64);
            bool win = (ov < v) || (ov == v && ok < kk);
            float loser = win ? v : ov;
            v2 = fminf(fminf(v2, ov2), loser);
            if (win) { v = ov; kk = ok; }
        }
        if (l31 == 0) {
            int row = wrow + (r & 3) + 8 * (r >> 2) + 4 * hl;   // C-layout row
            bks[row] = kk;
            if (v2 - v < MARGIN_D) {
                int p = atomicAdd(&nflag, 1);
                flagl[p] = row;
            }
        }
    }

    // zero-fill this block's encodings rows (128*1024 f32; region 4B-aligned only)
    {
        float* ep = out + ENC_OFF + (size_t)base * K_EMB;   // float idx ≡ 1 (mod 4)
        float4 z = make_float4(0.f, 0.f, 0.f, 0.f);
        float4* ap = reinterpret_cast<float4*>(ep + 3);
        for (int i = tid; i < 32767; i += 256) ap[i] = z;
        if (tid == 0) { ep[0] = 0.f; ep[1] = 0.f; ep[2] = 0.f; ep[131071] = 0.f; }
    }
    __syncthreads();   // bks + flags visible; zero-fill ordered before one-hot

    // in-block exact fp64 rescore of ambiguous rows (typically 0-2 per block)
    int nf = nflag;
#pragma unroll 1
    for (int fi = 0; fi < nf; ++fi) {
        int row = flagl[fi];
        if (tid < 16)
            *reinterpret_cast<float4*>(&xs2[tid * 4]) =
                reinterpret_cast<const float4*>(in + (size_t)(base + row) * D)[tid];
        __syncthreads();
        double bv = 1e300; int bk = 0;
#pragma unroll 1
        for (int c = 0; c < 4; ++c) {
            int k = tid * 4 + c;
            const float4* er = reinterpret_cast<const float4*>(emb + (size_t)k * D);
            double dot = 0.0, en = 0.0;
#pragma unroll 4
            for (int i = 0; i < 16; ++i) {
                float4 ev = er[i];
                float4 xv = *reinterpret_cast<const float4*>(&xs2[i * 4]);
                double e0 = ev.x, e1 = ev.y, e2 = ev.z, e3 = ev.w;
                en  = fma(e0, e0, en);  en  = fma(e1, e1, en);
                en  = fma(e2, e2, en);  en  = fma(e3, e3, en);
                dot = fma((double)xv.x, e0, dot); dot = fma((double)xv.y, e1, dot);
                dot = fma((double)xv.z, e2, dot); dot = fma((double)xv.w, e3, dot);
            }
            double s = fma(-2.0, dot, en);
            if (s < bv) { bv = s; bk = k; }      // k ascending -> first index
        }
        {
            double v = bv; int kk = bk;
#pragma unroll
            for (int off = 32; off >= 1; off >>= 1) {
                double ov = __shfl_xor(v, off, 64);
                int    ok = __shfl_xor(kk, off, 64);
                if (ov < v || (ov == v && ok < kk)) { v = ov; kk = ok; }
            }
            if (lane == 0) { rv[w] = v; rk[w] = kk; }
        }
        __syncthreads();
        if (tid == 0) {
            double v = rv[0]; int kk = rk[0];
#pragma unroll
            for (int x = 1; x < 4; ++x) {
                double ov = rv[x]; int ok = rk[x];
                if (ov < v || (ov == v && ok < kk)) { v = ov; kk = ok; }
            }
            bks[row] = kk;
        }
        __syncthreads();
    }

    // one-hot + counts
    if (tid < M_TILE) {
        int kk = bks[tid];
        atomicAdd(&counts[kk], 1u);
        out[ENC_OFF + (size_t)(base + tid) * K_EMB + kk] = 1.0f;
    }
    // quantized copy (both outputs identical): 2 threads per row
    {
        int row = tid >> 1;
        int p   = tid & 1;
        int kk  = bks[row];
        const float4* er = reinterpret_cast<const float4*>(emb + (size_t)kk * D);
        float4* o1 = reinterpret_cast<float4*>(out + Q_ST_OFF + (size_t)(base + row) * D);
        float4* o2 = reinterpret_cast<float4*>(out + Q_OR_OFF + (size_t)(base + row) * D);
#pragma unroll
        for (int i = 0; i < 8; ++i) {
            float4 v = er[p * 8 + i];
            o1[p * 8 + i] = v;
            o2[p * 8 + i] = v;
        }
    }
}

__global__ __launch_bounds__(1024) void perp_kernel(const unsigned int* __restrict__ counts,
                                                    float* __restrict__ out_perp) {
    const int k = threadIdx.x;
    double p = (double)counts[k] * (1.0 / (double)N_ROWS);
    double t = p * log(p + 1e-10);
#pragma unroll
    for (int off = 32; off >= 1; off >>= 1) t += __shfl_down(t, off, 64);
    __shared__ double red[16];
    if ((k & 63) == 0) red[k >> 6] = t;
    __syncthreads();
    if (k < 16) {
        double s = red[k];
#pragma unroll
        for (int off = 8; off >= 1; off >>= 1) s += __shfl_down(s, off, 16);
        if (k == 0) out_perp[0] = (float)exp(-s);
    }
}

extern "C" void kernel_launch(void* const* d_in, const int* in_sizes, int n_in,
                              void* d_out, int out_size, void* d_ws, size_t ws_size,
                              hipStream_t stream) {
    const float* in  = (const float*)d_in[0];
    const float* emb = (const float*)d_in[1];
    float* out = (float*)d_out;
    unsigned int* counts = (unsigned int*)d_ws;
    float* enorm32       = (float*)((char*)d_ws + 8192);

    hipMemsetAsync(d_ws, 0, 4096, stream);   // counts
    enorm32_kernel<<<K_EMB / 256, 256, 0, stream>>>(emb, enorm32);
    vq_main<<<N_ROWS / M_TILE, 256, 0, stream>>>(in, emb, enorm32, counts, out);
    perp_kernel<<<1, 1024, 0, stream>>>(counts, out + PERP_OFF);
}